// Round 3
// baseline (183.941 us; speedup 1.0000x reference)
//
#include <hip/hip_runtime.h>

// Problem constants (fixed by setup_inputs in the reference):
//   feature_map: (1, 256, 256, 256) fp32, NHWC   (67 MB — fits in 256 MB L3)
//   rois:        (2000, 5) int32  [batch, x, y, w, h]
//   pool_size:   7
#define FH 256
#define FW 256
#define FC 256
#define POOL 7

// Native vector type — required by __builtin_nontemporal_store (HIP's float4
// is a class and is rejected by the builtin).
typedef float f32x4 __attribute__((ext_vector_type(4)));

// One wave (64 lanes) per output cell (roi, pj, pi); each lane handles 4
// channels via float4 (256 ch / 4 = 64 = exactly one wave). The cell index
// is wave-uniform, so ROI metadata goes through s_load and the bilinear
// coordinate math is scalar; every global access is a coalesced 16B/lane op.
// Output is write-once → non-temporal store keeps the feature map resident
// in L2/L3 instead of being evicted by the 98 MB output stream.
__global__ __launch_bounds__(256) void roi_pool_kernel(
    const float* __restrict__ fm,
    const int*   __restrict__ rois,
    float*       __restrict__ out,
    int n_cells)
{
    int t    = blockIdx.x * blockDim.x + threadIdx.x;
    int lane = threadIdx.x & 63;               // float4 channel-group index
    int cell = __builtin_amdgcn_readfirstlane(t >> 6);  // wave-uniform (roi,pj,pi)
    if (cell >= n_cells) return;

    int pi  = cell % POOL;
    int tmp = cell / POOL;
    int pj  = tmp % POOL;
    int roi = tmp / POOL;

    int rx = rois[roi * 5 + 1];
    int ry = rois[roi * 5 + 2];
    int rw = rois[roi * 5 + 3];
    int rh = rois[roi * 5 + 4];

    // y-axis sample coords (half-pixel centers of bilinear resize of the
    // crop [ry, ry+rh) to POOL rows), matching the reference exactly.
    float lfh = (float)rh;
    float fy  = ((float)pj + 0.5f) * (lfh / (float)POOL) - 0.5f;
    fy = fminf(fmaxf(fy, 0.0f), lfh - 1.0f);
    int   j0 = (int)floorf(fy);
    int   j1 = min(j0 + 1, rh - 1);
    float wy = fy - (float)j0;
    int   y0 = ry + j0;
    int   y1 = ry + j1;

    // x-axis
    float lfw = (float)rw;
    float fx  = ((float)pi + 0.5f) * (lfw / (float)POOL) - 0.5f;
    fx = fminf(fmaxf(fx, 0.0f), lfw - 1.0f);
    int   i0 = (int)floorf(fx);
    int   i1 = min(i0 + 1, rw - 1);
    float wx = fx - (float)i0;
    int   x0 = rx + i0;
    int   x1 = rx + i1;

    const f32x4* p00 = (const f32x4*)(fm + ((size_t)y0 * FW + x0) * FC) + lane;
    const f32x4* p01 = (const f32x4*)(fm + ((size_t)y0 * FW + x1) * FC) + lane;
    const f32x4* p10 = (const f32x4*)(fm + ((size_t)y1 * FW + x0) * FC) + lane;
    const f32x4* p11 = (const f32x4*)(fm + ((size_t)y1 * FW + x1) * FC) + lane;

    f32x4 a = *p00;
    f32x4 b = *p01;
    f32x4 c = *p10;
    f32x4 d = *p11;

    float owx = 1.0f - wx;
    float owy = 1.0f - wy;

    f32x4 r = (a * owx + b * wx) * owy + (c * owx + d * wx) * wy;

    f32x4* o = (f32x4*)(out + (size_t)cell * FC) + lane;
    __builtin_nontemporal_store(r, o);   // write-once stream — don't cache
}

extern "C" void kernel_launch(void* const* d_in, const int* in_sizes, int n_in,
                              void* d_out, int out_size, void* d_ws, size_t ws_size,
                              hipStream_t stream) {
    const float* fm   = (const float*)d_in[0];
    const int*   rois = (const int*)d_in[1];
    // d_in[2] is pool_size (==7), fixed by the problem; hardcoded as POOL.
    float* out = (float*)d_out;

    int n_rois  = in_sizes[1] / 5;
    int n_cells = n_rois * POOL * POOL;          // 98000
    int total   = n_cells * (FC / 4);            // one thread per float4
    int block   = 256;
    int grid    = (total + block - 1) / block;

    roi_pool_kernel<<<grid, block, 0, stream>>>(fm, rois, out, n_cells);
}

// Round 4
// 183.116 us; speedup vs baseline: 1.0045x; 1.0045x over previous
//
#include <hip/hip_runtime.h>

// Problem constants (fixed by setup_inputs in the reference):
//   feature_map: (1, 256, 256, 256) fp32, NHWC   (67 MB — fits in 256 MB L3)
//   rois:        (2000, 5) int32  [batch, x, y, w, h]
//   pool_size:   7
#define FH 256
#define FW 256
#define FC 256
#define POOL 7
#define CPW 4   // cells per wave

// Native vector type — required by __builtin_nontemporal_store.
typedef float f32x4 __attribute__((ext_vector_type(4)));

// One wave handles CPW consecutive output cells; 64 lanes × float4 = 256
// channels per cell. All 4*CPW loads are issued before any blend/store (ILP
// to cover memory latency). blockIdx is inverse-swizzled so logically
// consecutive cells (same ROI) run on the SAME XCD — keeps a ROI's ~150 KB
// read set inside one per-XCD L2 instead of smearing it across all 8.
__global__ __launch_bounds__(256) void roi_pool_kernel(
    const float* __restrict__ fm,
    const int*   __restrict__ rois,
    float*       __restrict__ out,
    int n_cells, int chunk)
{
    // HW maps block b -> XCD (b % 8); remap so logical block lb is
    // contiguous per XCD: XCD k gets lb in [k*chunk, (k+1)*chunk).
    int b  = blockIdx.x;
    int lb = (b & 7) * chunk + (b >> 3);

    int lane = threadIdx.x & 63;               // float4 channel-group index
    int wave = threadIdx.x >> 6;               // wave within block (0..3)
    int base_cell = __builtin_amdgcn_readfirstlane((lb * 4 + wave) * CPW);
    if (base_cell >= n_cells) return;          // n_cells % CPW == 0

    f32x4 A[CPW], B[CPW], C[CPW], D[CPW];
    float WX[CPW], WY[CPW];

#pragma unroll
    for (int c = 0; c < CPW; ++c) {
        int cell = base_cell + c;              // wave-uniform
        int pi  = cell % POOL;
        int tmp = cell / POOL;
        int pj  = tmp % POOL;
        int roi = tmp / POOL;

        int rx = rois[roi * 5 + 1];
        int ry = rois[roi * 5 + 2];
        int rw = rois[roi * 5 + 3];
        int rh = rois[roi * 5 + 4];

        // Half-pixel-center bilinear coords of crop resize (matches ref).
        float lfh = (float)rh;
        float fy  = ((float)pj + 0.5f) * (lfh / (float)POOL) - 0.5f;
        fy = fminf(fmaxf(fy, 0.0f), lfh - 1.0f);
        int   j0 = (int)floorf(fy);
        int   j1 = min(j0 + 1, rh - 1);
        WY[c] = fy - (float)j0;
        int   y0 = ry + j0;
        int   y1 = ry + j1;

        float lfw = (float)rw;
        float fx  = ((float)pi + 0.5f) * (lfw / (float)POOL) - 0.5f;
        fx = fminf(fmaxf(fx, 0.0f), lfw - 1.0f);
        int   i0 = (int)floorf(fx);
        int   i1 = min(i0 + 1, rw - 1);
        WX[c] = fx - (float)i0;
        int   x0 = rx + i0;
        int   x1 = rx + i1;

        A[c] = *((const f32x4*)(fm + ((size_t)y0 * FW + x0) * FC) + lane);
        B[c] = *((const f32x4*)(fm + ((size_t)y0 * FW + x1) * FC) + lane);
        C[c] = *((const f32x4*)(fm + ((size_t)y1 * FW + x0) * FC) + lane);
        D[c] = *((const f32x4*)(fm + ((size_t)y1 * FW + x1) * FC) + lane);
    }

#pragma unroll
    for (int c = 0; c < CPW; ++c) {
        float wx = WX[c], wy = WY[c];
        float owx = 1.0f - wx, owy = 1.0f - wy;
        f32x4 r = (A[c] * owx + B[c] * wx) * owy
                + (C[c] * owx + D[c] * wx) * wy;
        f32x4* o = (f32x4*)(out + (size_t)(base_cell + c) * FC) + lane;
        __builtin_nontemporal_store(r, o);     // write-once stream
    }
}

extern "C" void kernel_launch(void* const* d_in, const int* in_sizes, int n_in,
                              void* d_out, int out_size, void* d_ws, size_t ws_size,
                              hipStream_t stream) {
    const float* fm   = (const float*)d_in[0];
    const int*   rois = (const int*)d_in[1];
    // d_in[2] is pool_size (==7), fixed by the problem; hardcoded as POOL.
    float* out = (float*)d_out;

    int n_rois  = in_sizes[1] / 5;
    int n_cells = n_rois * POOL * POOL;              // 98000 (divisible by CPW)
    int n_waves = (n_cells + CPW - 1) / CPW;         // 24500
    int blocks  = (n_waves + 3) / 4;                 // 4 waves per block -> 6125
    blocks      = (blocks + 7) & ~7;                 // pad to multiple of 8 -> 6128
    int chunk   = blocks / 8;                        // logical blocks per XCD

    roi_pool_kernel<<<blocks, 256, 0, stream>>>(fm, rois, out, n_cells, chunk);
}